// Round 1
// baseline (235.897 us; speedup 1.0000x reference)
//
#include <hip/hip_runtime.h>

// out[b,h,w,u] = sum_d (w[u,d] - x[b,h,w,d])^2
//              = ||x||^2 - 2 x.w + ||w||^2
// x: [524288, 64] fp32 (134 MB, read once), w: [64, 64] fp32 (16 KB),
// out: [524288, 64] fp32 (134 MB, written once). Memory-bound: ~43 us floor.
//
// Strategy: per-wave 16-row x 64-unit tile via mfma_f32_16x16x32_bf16.
//   A operand = w   (M-dim = units; 8 frags live in registers all kernel)
//   B operand = x   (N-dim = rows; loaded global->reg as 4x dwordx4/lane)
// C/D layout (verified, guide m89): col = lane&15 (row index), row = quad*4+reg
// (unit index) -> each lane holds 4 consecutive units -> dwordx4 stores.
// ||x||^2, ||w||^2 computed in fp32 from originals; only the cross term is bf16.

typedef float  float4v  __attribute__((ext_vector_type(4)));
typedef __bf16 bf16x8   __attribute__((ext_vector_type(8)));

static constexpr int kRows  = 16 * 128 * 256;  // 524288
static constexpr int kTiles = kRows / 16;      // 32768

__device__ __forceinline__ bf16x8 cvt2(float4v a, float4v b) {
  bf16x8 r;
  r[0] = (__bf16)a[0]; r[1] = (__bf16)a[1]; r[2] = (__bf16)a[2]; r[3] = (__bf16)a[3];
  r[4] = (__bf16)b[0]; r[5] = (__bf16)b[1]; r[6] = (__bf16)b[2]; r[7] = (__bf16)b[3];
  return r;
}

__global__ __launch_bounds__(256) void sqdist_kernel(
    const float* __restrict__ X, const float* __restrict__ W,
    float* __restrict__ Out) {
  const int lane = threadIdx.x & 63;
  const int q    = lane >> 4;   // quad 0..3
  const int m    = lane & 15;

  // ---- Setup: w fragments (A operand) + redistributed ||w||^2 ----
  // A layout: A[mdim = lane&15][k = q*8 + j]; frag kf covers k in [32*kf, 32*kf+32).
  bf16x8 aw[4][2];
  float  w2adj[4][4];  // [ut][reg]: ||w_u||^2 for u = 16*ut + q*4 + reg
#pragma unroll
  for (int ut = 0; ut < 4; ++ut) {
    const float4v* wr = (const float4v*)(W + (ut * 16 + m) * 64);
    float4v v0 = wr[q * 2];
    float4v v1 = wr[q * 2 + 1];
    float4v v2 = wr[8 + q * 2];
    float4v v3 = wr[8 + q * 2 + 1];
    aw[ut][0] = cvt2(v0, v1);
    aw[ut][1] = cvt2(v2, v3);
    float s = 0.f;
#pragma unroll
    for (int i = 0; i < 4; ++i)
      s += v0[i] * v0[i] + v1[i] * v1[i] + v2[i] * v2[i] + v3[i] * v3[i];
    s += __shfl_xor(s, 16);      // reduce across quads (lanes m, m+16, m+32, m+48)
    s += __shfl_xor(s, 32);      // -> every lane holds ||w_(16*ut+m)||^2
#pragma unroll
    for (int r = 0; r < 4; ++r)
      w2adj[ut][r] = __shfl(s, q * 4 + r);  // fetch ||w||^2 of the unit this C-reg maps to
  }

  const int gw = blockIdx.x * (blockDim.x >> 6) + (threadIdx.x >> 6);
  const int nw = gridDim.x * (blockDim.x >> 6);

  for (int tile = gw; tile < kTiles; tile += nw) {
    // ---- Load this lane's slice of the 16-row x-tile (B operand) ----
    // B layout: B[k = q*8 + j][ndim = lane&15]; lane reads row (tile*16+m),
    // floats [q*8 .. q*8+7] and [32+q*8 .. 32+q*8+7]. Every byte read once.
    const float4v* xr = (const float4v*)(X + (tile * 16 + m) * 64);
    float4v x0 = xr[q * 2];
    float4v x1 = xr[q * 2 + 1];
    float4v x2 = xr[8 + q * 2];
    float4v x3 = xr[8 + q * 2 + 1];

    // ||x_row||^2 in fp32 (partial over this lane's 16 elems, reduce over quads)
    float s = 0.f;
#pragma unroll
    for (int i = 0; i < 4; ++i)
      s += x0[i] * x0[i] + x1[i] * x1[i] + x2[i] * x2[i] + x3[i] * x3[i];
    s += __shfl_xor(s, 16);
    s += __shfl_xor(s, 32);      // s = ||x_(tile*16+m)||^2 ; C-col of this lane is m -> no shfl

    bf16x8 bx0 = cvt2(x0, x1);
    bf16x8 bx1 = cvt2(x2, x3);

    // ---- 8 MFMAs: acc[ut][reg] = dot(w[16*ut + q*4 + reg], x[tile*16 + m]) ----
    float4v acc[4];
#pragma unroll
    for (int ut = 0; ut < 4; ++ut) {
      float4v z = {0.f, 0.f, 0.f, 0.f};
      acc[ut] = __builtin_amdgcn_mfma_f32_16x16x32_bf16(aw[ut][0], bx0, z, 0, 0, 0);
      acc[ut] = __builtin_amdgcn_mfma_f32_16x16x32_bf16(aw[ut][1], bx1, acc[ut], 0, 0, 0);
    }

    // ---- Epilogue: out = x2 + w2 - 2*dot ; 4x dwordx4 coalesced stores ----
    float4v* orow = (float4v*)(Out + (tile * 16 + m) * 64);
#pragma unroll
    for (int ut = 0; ut < 4; ++ut) {
      float4v o;
#pragma unroll
      for (int r = 0; r < 4; ++r)
        o[r] = fmaf(-2.f, acc[ut][r], s + w2adj[ut][r]);
      orow[ut * 4 + q] = o;   // floats [16*ut + 4*q .. +3] of this row
    }
  }
}

extern "C" void kernel_launch(void* const* d_in, const int* in_sizes, int n_in,
                              void* d_out, int out_size, void* d_ws, size_t ws_size,
                              hipStream_t stream) {
  const float* X = (const float*)d_in[0];
  const float* W = (const float*)d_in[1];
  float* Out = (float*)d_out;
  // 1024 blocks x 4 waves = 4096 waves; 32768 tiles -> 8 tiles/wave, grid-stride.
  sqdist_kernel<<<1024, 256, 0, stream>>>(X, W, Out);
}